// Round 2
// baseline (1430.546 us; speedup 1.0000x reference)
//
#include <hip/hip_runtime.h>
#include <stdint.h>

#define TOKENS 8192
#define IN_F   4096
#define OUT_F  11008
#define GROUPSIZE 128

#define BM 128
#define BN 128
#define BK 32

typedef __attribute__((ext_vector_type(8))) short          bf16x8;
typedef __attribute__((ext_vector_type(4))) float          f32x4;
typedef __attribute__((ext_vector_type(8))) unsigned short u16x8;

static __device__ __forceinline__ unsigned short f2bf(float f) {
    union { float f; unsigned int u; } v; v.f = f;
    unsigned int u = v.u;
    u += 0x7fffu + ((u >> 16) & 1u);   // round-to-nearest-even
    return (unsigned short)(u >> 16);
}

// ---------------------------------------------------------------- x -> bf16
__global__ void cvt_x_kernel(const float* __restrict__ x,
                             unsigned short* __restrict__ xb) {
    int i = (blockIdx.x * 256 + threadIdx.x) * 8;
    const float4* p = (const float4*)(x + i);
    float4 a = p[0];
    float4 b = p[1];
    u16x8 o;
    o[0] = f2bf(a.x); o[1] = f2bf(a.y); o[2] = f2bf(a.z); o[3] = f2bf(a.w);
    o[4] = f2bf(b.x); o[5] = f2bf(b.y); o[6] = f2bf(b.z); o[7] = f2bf(b.w);
    *(u16x8*)(xb + i) = o;
}

// ------------------------------------------- dequant int4 -> bf16, W_t[N][K]
// grid: (OUT_F/32, 512/8). Thread t: n = bx*32 + t>>3, packed-row kp = by*8 + (t&7).
// Writes: 8 consecutive lanes cover 8*16B = 128B contiguous of one n-row (coalesced).
__global__ void dequant_kernel(const int* __restrict__ qweight,
                               const int* __restrict__ qzeros,
                               const float* __restrict__ scales,
                               unsigned short* __restrict__ Wt) {
    const int t  = threadIdx.x;
    const int n  = blockIdx.x * 32 + (t >> 3);
    const int kp = blockIdx.y * 8 + (t & 7);
    const int g  = blockIdx.y >> 1;            // (by*8)>>4 : uniform per block
    const float s  = scales[g * OUT_F + n];
    const int   zq = ((qzeros[g * (OUT_F / 8) + (n >> 3)] >> (4 * (n & 7))) & 0xF) + 1;
    const float zs = (float)zq * s;            // w = nib*s - zs
    const int qw = qweight[kp * OUT_F + n];
    u16x8 o;
#pragma unroll
    for (int j = 0; j < 8; ++j)
        o[j] = f2bf(fmaf((float)((qw >> (4 * j)) & 0xF), s, -zs));
    *(u16x8*)(Wt + (size_t)n * IN_F + kp * 8) = o;
}

// -------------------------------------------------------------- bf16 GEMM
// C[M][N] = A[M][K] * Bt[N][K]^T + bias ; m97 structure
#define GLD16(gp, lp)                                                        \
    __builtin_amdgcn_global_load_lds(                                        \
        (const __attribute__((address_space(1))) unsigned int*)(gp),         \
        (__attribute__((address_space(3))) unsigned int*)(lp), 16, 0, 0)

__global__ __launch_bounds__(256) void gemm_bias_kernel(
    const unsigned short* __restrict__ A,   // [TOKENS][IN_F] bf16
    const unsigned short* __restrict__ Bt,  // [OUT_F][IN_F]  bf16
    const float* __restrict__ bias,
    float* __restrict__ C) {
    __shared__ unsigned short As[BM * BK];
    __shared__ unsigned short Bs[BN * BK];

    const int t    = threadIdx.x;
    const int lane = t & 63;
    const int wave = t >> 6;

    const int m0 = blockIdx.y * BM;
    const int n0 = blockIdx.x * BN;
    const int wm = (wave & 1) * 64;   // wave's 64x64 sub-tile
    const int wn = (wave >> 1) * 64;

    f32x4 acc[4][4] = {};

    // staging: per wave, LDS dst = wave_base + lane*16B (contiguous, GLD-safe)
    const int srow = wave * 16 + (lane >> 2);      // row within tile (chunk 0)
    const int scol = (lane & 3) * 8;               // bf16 elem offset within row

    const unsigned short* a_g0 = A  + (size_t)(m0 + srow)      * IN_F + scol;
    const unsigned short* a_g1 = A  + (size_t)(m0 + srow + 64) * IN_F + scol;
    const unsigned short* b_g0 = Bt + (size_t)(n0 + srow)      * IN_F + scol;
    const unsigned short* b_g1 = Bt + (size_t)(n0 + srow + 64) * IN_F + scol;

    unsigned short* a_l0 = &As[srow * BK + scol];
    unsigned short* a_l1 = &As[(srow + 64) * BK + scol];
    unsigned short* b_l0 = &Bs[srow * BK + scol];
    unsigned short* b_l1 = &Bs[(srow + 64) * BK + scol];

    const int frow = lane & 15;            // fragment row within 16
    const int fk   = (lane >> 4) * 8;      // fragment k offset

    for (int kt = 0; kt < IN_F; kt += BK) {
        GLD16(a_g0 + kt, a_l0);
        GLD16(a_g1 + kt, a_l1);
        GLD16(b_g0 + kt, b_l0);
        GLD16(b_g1 + kt, b_l1);
        __syncthreads();   // drains vmcnt -> staged tile visible

        bf16x8 a_frag[4], b_frag[4];
#pragma unroll
        for (int i = 0; i < 4; ++i)
            a_frag[i] = *(const bf16x8*)&As[(wm + i * 16 + frow) * BK + fk];
#pragma unroll
        for (int j = 0; j < 4; ++j)
            b_frag[j] = *(const bf16x8*)&Bs[(wn + j * 16 + frow) * BK + fk];
#pragma unroll
        for (int i = 0; i < 4; ++i)
#pragma unroll
            for (int j = 0; j < 4; ++j)
                acc[i][j] = __builtin_amdgcn_mfma_f32_16x16x32_bf16(
                    a_frag[i], b_frag[j], acc[i][j], 0, 0, 0);
        __syncthreads();   // tile consumed, safe to overwrite
    }

    // epilogue: C/D layout col=lane&15, row=(lane>>4)*4+reg
    const int col = lane & 15;
    const int r0  = (lane >> 4) * 4;
#pragma unroll
    for (int j = 0; j < 4; ++j) {
        const int n = n0 + wn + j * 16 + col;
        const float bv = bias[n];
#pragma unroll
        for (int i = 0; i < 4; ++i) {
            const int m = m0 + wm + i * 16 + r0;
#pragma unroll
            for (int r = 0; r < 4; ++r)
                C[(size_t)(m + r) * OUT_F + n] = acc[i][j][r] + bv;
        }
    }
}

// ---------------------------------------------- zero-workspace fallback
// Only used if ws_size is too small for the staging buffers. Correct, slow.
__global__ __launch_bounds__(256) void fallback_kernel(
    const float* __restrict__ x, const int* __restrict__ qweight,
    const int* __restrict__ qzeros, const float* __restrict__ scales,
    const float* __restrict__ bias, float* __restrict__ C) {
    const int n = blockIdx.x * 16 + (threadIdx.x & 15);
    const int m = blockIdx.y * 16 + (threadIdx.x >> 4);
    float acc = 0.f;
    const float* xr = x + (size_t)m * IN_F;
    for (int g = 0; g < IN_F / GROUPSIZE; ++g) {
        const float s  = scales[g * OUT_F + n];
        const float zs = s * (float)(((qzeros[g * (OUT_F / 8) + (n >> 3)]
                                       >> (4 * (n & 7))) & 0xF) + 1);
        for (int kp = g * 16; kp < g * 16 + 16; ++kp) {
            const int qw = qweight[kp * OUT_F + n];
#pragma unroll
            for (int j = 0; j < 8; ++j) {
                const float w = fmaf((float)((qw >> (4 * j)) & 0xF), s, -zs);
                acc = fmaf(xr[kp * 8 + j], w, acc);
            }
        }
    }
    C[(size_t)m * OUT_F + n] = acc + bias[n];
}

extern "C" void kernel_launch(void* const* d_in, const int* in_sizes, int n_in,
                              void* d_out, int out_size, void* d_ws, size_t ws_size,
                              hipStream_t stream) {
    const float* x       = (const float*)d_in[0];
    const int*   qweight = (const int*)  d_in[1];
    const int*   qzeros  = (const int*)  d_in[2];
    const float* scales  = (const float*)d_in[3];
    // d_in[4] = g_idx (contents are arange(IN_F)//GROUPSIZE; computed inline)
    const float* bias    = (const float*)d_in[5];
    float* out = (float*)d_out;

    const size_t xb_bytes = (size_t)TOKENS * IN_F * sizeof(unsigned short); // 67.1 MB
    const size_t wt_bytes = (size_t)OUT_F  * IN_F * sizeof(unsigned short); // 90.2 MB

    if (ws_size >= xb_bytes + wt_bytes) {
        unsigned short* xb = (unsigned short*)d_ws;
        unsigned short* Wt = (unsigned short*)((char*)d_ws + xb_bytes);
        cvt_x_kernel<<<(TOKENS * IN_F) / (256 * 8), 256, 0, stream>>>(x, xb);
        dequant_kernel<<<dim3(OUT_F / 32, IN_F / 8 / 8), 256, 0, stream>>>(
            qweight, qzeros, scales, Wt);
        gemm_bias_kernel<<<dim3(OUT_F / BN, TOKENS / BM), 256, 0, stream>>>(
            xb, Wt, bias, out);
    } else {
        fallback_kernel<<<dim3(OUT_F / 16, TOKENS / 16), 256, 0, stream>>>(
            x, qweight, qzeros, scales, bias, out);
    }
}